// Round 1
// baseline (10194.202 us; speedup 1.0000x reference)
//
#include <hip/hip_runtime.h>
#include <math.h>

#define T_LEN 512

// ---------------- workspace layout (bytes) ----------------
// 0x0000 : unsigned barrier counter (memset 0 each launch)
// 0x0100 : float null_attn[5]
// 0x0200 : float kc_g[5*32]
// 0x0600 : float vc_g[5*128]           (ends exactly at 0x1000)
// 0x1000 : float keys[512*6*64]        (786432 B)
// 0x1000+0xC0000 : float vals[512*6*64]
// 0x1000+2*0xC0000 : float hidden[512*640]

// ============ kernel 1: key/value projections (parallel) ============
__global__ __launch_bounds__(128) void precompute_kv(
    const float* __restrict__ bert, const int* __restrict__ uidx, const int* __restrict__ pidx,
    const float* __restrict__ disg, const float* __restrict__ udisg,
    const float* __restrict__ utab, const float* __restrict__ ptab,
    const float* __restrict__ Wk0, const float* __restrict__ Wv0,
    const float* __restrict__ Wk1, const float* __restrict__ Wv1,
    const float* __restrict__ Wk2, const float* __restrict__ Wv2,
    const float* __restrict__ Wk3, const float* __restrict__ Wv3,
    const float* __restrict__ Wk4, const float* __restrict__ Wv4,
    float* __restrict__ keys, float* __restrict__ vals)
{
    __shared__ float x[768 + 50 + 20 + 2 + 2];
    const int t = blockIdx.x, tid = threadIdx.x;
    for (int i = tid; i < 768; i += 128) x[i] = bert[t * 768 + i];
    const int u = uidx[t], p = pidx[t];
    for (int i = tid; i < 50; i += 128) x[768 + i] = utab[u * 50 + i];
    for (int i = tid; i < 20; i += 128) x[818 + i] = ptab[p * 20 + i];
    if (tid < 2) x[838 + tid] = disg[t * 2 + tid];
    if (tid >= 2 && tid < 4) x[840 + (tid - 2)] = udisg[t * 2 + (tid - 2)];
    __syncthreads();
    const int j = tid & 63, isv = tid >> 6;
    float* outb = (isv ? vals : keys) + t * 384;
    {   const float* W = isv ? Wv0 : Wk0; float a = 0.f;
        for (int i = 0; i < 768; ++i) a += x[i] * W[i * 64 + j];
        outb[0 * 64 + j] = a; }
    {   const float* W = isv ? Wv1 : Wk1; float a = 0.f;
        for (int i = 0; i < 50; ++i) a += x[768 + i] * W[i * 64 + j];
        outb[1 * 64 + j] = a; }
    {   const float* W = isv ? Wv2 : Wk2; float a = 0.f;
        for (int i = 0; i < 20; ++i) a += x[818 + i] * W[i * 64 + j];
        outb[2 * 64 + j] = a; }
    {   const float* W = isv ? Wv3 : Wk3;
        outb[3 * 64 + j] = x[838] * W[j] + x[839] * W[64 + j]; }
    {   const float* W = isv ? Wv4 : Wk4;
        outb[4 * 64 + j] = x[840] * W[j] + x[841] * W[64 + j]; }
    outb[5 * 64 + j] = 0.f;   // null key/value row (ws is poisoned, must zero)
}

// ============ kernel 2: the sequential RIM scan ============
// grid = 5 blocks (one per mechanism), 512 threads.
// Per-mech weights: Wq/Wqc/Wkc/Wvc/b in LDS (fp32, ~134 KB dynamic);
// Wih (64 f) + Whh (128 f) per thread in VGPRs (thread j owns gate column j).
// 2 device-scope barriers/step; barrier A (mask) hidden behind gates compute.

#define SMEM_FLOATS 34208   // see offsets below

__global__ __launch_bounds__(512, 2) void rim_scan(
    const float* __restrict__ Wq, const float* __restrict__ Wih, const float* __restrict__ Whh,
    const float* __restrict__ b_lstm, const float* __restrict__ Wqc, const float* __restrict__ Wkc,
    const float* __restrict__ Wvc,
    const float* __restrict__ keys, const float* __restrict__ vals,
    float* __restrict__ hidden,
    unsigned* __restrict__ bar, float* __restrict__ null_g,
    float* __restrict__ kc_g, float* __restrict__ vc_g)
{
    extern __shared__ float sm[];
    float* sWq  = sm;            // 8192  : Wq[m]  [128][64]
    float* sWqc = sm + 8192;     // 4096  : Wqc[m] [128][32]
    float* sWkc = sm + 12288;    // 4096  : Wkc[m] [128][32]
    float* sWvc = sm + 16384;    // 16384 : Wvc[m] [128][128]
    float* sb   = sm + 32768;    // 512
    float* sg   = sm + 33280;    // 512 gates
    float* sh   = sm + 33792;    // 128 h state
    float* sc   = sm + 33920;    // 128 c state
    float* sinp = sm + 34048;    // 64
    float* sq   = sm + 34112;    // 64  (q, later qc[0:32] / kc-local[32:64])
    float* sattn= sm + 34176;    // 8   (raw logits then attn probs, 6 used)
    float* sclog= sm + 34184;    // 8   context-attn logits
    float* scat = sm + 34192;    // 8   context-attn probs
    float* snull= sm + 34200;    // 8   null_attn of all mechs

    const int mech = blockIdx.x, tid = threadIdx.x;

    // ---- stage weights
    for (int i = tid; i < 8192;  i += 512) sWq[i]  = Wq[mech * 8192 + i];
    for (int i = tid; i < 4096;  i += 512) sWqc[i] = Wqc[mech * 4096 + i];
    for (int i = tid; i < 4096;  i += 512) sWkc[i] = Wkc[mech * 4096 + i];
    for (int i = tid; i < 16384; i += 512) sWvc[i] = Wvc[mech * 16384 + i];
    sb[tid] = b_lstm[mech * 512 + tid];
    if (tid < 128) { sh[tid] = 0.f; sc[tid] = 0.f; }
    float wih[64], whh[128];
    #pragma unroll
    for (int i = 0; i < 64;  ++i) wih[i] = Wih[mech * (64 * 512) + i * 512 + tid];
    #pragma unroll
    for (int i = 0; i < 128; ++i) whh[i] = Whh[mech * (128 * 512) + i * 512 + tid];
    __syncthreads();

    const float inv_sdk = 0.125f;                  // 1/sqrt(64)
    const float inv_sdc = 0.17677669529663687f;    // 1/sqrt(32)

    #pragma unroll 1
    for (int t = 0; t < T_LEN; ++t) {
        // ---- q = h @ Wq[m] : 64 outputs x 8 threads each
        {
            const int j = tid >> 3, s = tid & 7;
            float p = 0.f;
            #pragma unroll
            for (int ii = 0; ii < 16; ++ii) { int i = s * 16 + ii; p += sh[i] * sWq[i * 64 + j]; }
            p += __shfl_down(p, 4); p += __shfl_down(p, 2); p += __shfl_down(p, 1);
            if (s == 0) sq[j] = p;
        }
        __syncthreads();
        // ---- attn logits over 6 keys (incl. null)
        if (tid < 384) {
            const int key = tid >> 6, i = tid & 63;
            float p = sq[i] * keys[t * 384 + key * 64 + i];
            p += __shfl_down(p, 32); p += __shfl_down(p, 16); p += __shfl_down(p, 8);
            p += __shfl_down(p, 4);  p += __shfl_down(p, 2);  p += __shfl_down(p, 1);
            if (i == 0) sattn[key] = p * inv_sdk;
        }
        __syncthreads();
        if (tid == 0) {
            float mx = sattn[0];
            #pragma unroll
            for (int k = 1; k < 6; ++k) mx = fmaxf(mx, sattn[k]);
            float e[6], ssum = 0.f;
            #pragma unroll
            for (int k = 0; k < 6; ++k) { e[k] = __expf(sattn[k] - mx); ssum += e[k]; }
            const float inv = 1.f / ssum;
            #pragma unroll
            for (int k = 0; k < 6; ++k) sattn[k] = e[k] * inv;
            // publish null_attn and arrive at barrier A(t) — wait happens after gates
            __hip_atomic_store(&null_g[mech], sattn[5], __ATOMIC_RELAXED, __HIP_MEMORY_SCOPE_AGENT);
            __hip_atomic_fetch_add(bar, 1u, __ATOMIC_RELEASE, __HIP_MEMORY_SCOPE_AGENT);
        }
        __syncthreads();
        // ---- inp = attn @ vals (speculative: mask not needed yet)
        if (tid < 64) {
            float a = 0.f;
            #pragma unroll
            for (int k = 0; k < 6; ++k) a += sattn[k] * vals[t * 384 + k * 64 + tid];
            sinp[tid] = a;
        }
        __syncthreads();
        // ---- gates (thread = gate column, weights in registers)
        {
            float acc = sb[tid];
            #pragma unroll
            for (int i = 0; i < 64;  ++i) acc += sinp[i] * wih[i];
            #pragma unroll
            for (int i = 0; i < 128; ++i) acc += sh[i]  * whh[i];
            sg[tid] = acc;
        }
        __syncthreads();
        float cn = 0.f, hn = 0.f;
        if (tid < 128) {
            const float gi = sg[tid], gf = sg[128 + tid], gg = sg[256 + tid], go = sg[384 + tid];
            const float si = 1.f / (1.f + __expf(-gi));
            const float sf = 1.f / (1.f + __expf(-gf));
            const float so = 1.f / (1.f + __expf(-go));
            cn = sf * sc[tid] + si * tanhf(gg);
            hn = so * tanhf(cn);
        }
        // ---- complete barrier A, fetch all null_attn
        if (tid == 0) {
            const unsigned tgt = 10u * (unsigned)t + 5u;
            while (__hip_atomic_load(bar, __ATOMIC_ACQUIRE, __HIP_MEMORY_SCOPE_AGENT) < tgt)
                __builtin_amdgcn_s_sleep(1);
            #pragma unroll
            for (int mm = 0; mm < 5; ++mm)
                snull[mm] = __hip_atomic_load(&null_g[mm], __ATOMIC_RELAXED, __HIP_MEMORY_SCOPE_AGENT);
        }
        __syncthreads();
        // ---- mask: active iff null_attn among 3 smallest (stable, lower index wins)
        int rank = 0;
        {
            const float myn = snull[mech];
            #pragma unroll
            for (int mm = 0; mm < 5; ++mm) {
                const float o = snull[mm];
                rank += (o < myn || (o == myn && mm < mech)) ? 1 : 0;
            }
        }
        const bool active = (rank < 3);
        if (tid < 128 && active) { sc[tid] = cn; sh[tid] = hn; }
        __syncthreads();   // sh now holds h1
        // ---- qc (threads 0..255) and kc (threads 256..511)
        if (tid < 256) {
            const int out = tid >> 3, s = tid & 7;
            float p = 0.f;
            #pragma unroll
            for (int ii = 0; ii < 16; ++ii) { int i = s * 16 + ii; p += sh[i] * sWqc[i * 32 + out]; }
            p += __shfl_down(p, 4); p += __shfl_down(p, 2); p += __shfl_down(p, 1);
            if (s == 0) sq[out] = p;                 // qc in sq[0:32]
        } else {
            const int tt = tid - 256, out = tt >> 3, s = tt & 7;
            float p = 0.f;
            #pragma unroll
            for (int ii = 0; ii < 16; ++ii) { int i = s * 16 + ii; p += sh[i] * sWkc[i * 32 + out]; }
            p += __shfl_down(p, 4); p += __shfl_down(p, 2); p += __shfl_down(p, 1);
            if (s == 0) {
                sq[32 + out] = p;                    // local kc copy
                __hip_atomic_store(&kc_g[mech * 32 + out], p, __ATOMIC_RELAXED, __HIP_MEMORY_SCOPE_AGENT);
            }
        }
        // ---- vc = h1 @ Wvc[m] : 128 outputs x 4 threads
        {
            const int out = tid >> 2, s = tid & 3;
            float p = 0.f;
            #pragma unroll
            for (int ii = 0; ii < 32; ++ii) { int i = s * 32 + ii; p += sh[i] * sWvc[i * 128 + out]; }
            p += __shfl_down(p, 2); p += __shfl_down(p, 1);
            if (s == 0)
                __hip_atomic_store(&vc_g[mech * 128 + out], p, __ATOMIC_RELAXED, __HIP_MEMORY_SCOPE_AGENT);
        }
        __syncthreads();   // drains vmem (syncthreads waits vmcnt) -> stores visible pre-release
        if (tid == 0) {
            __hip_atomic_fetch_add(bar, 1u, __ATOMIC_RELEASE, __HIP_MEMORY_SCOPE_AGENT); // arrive B(t)
            const unsigned tgt = 10u * (unsigned)t + 10u;
            while (__hip_atomic_load(bar, __ATOMIC_ACQUIRE, __HIP_MEMORY_SCOPE_AGENT) < tgt)
                __builtin_amdgcn_s_sleep(1);
        }
        __syncthreads();
        // ---- context attention logits: row `mech` of qc @ kc.T
        if (tid < 160) {
            const int m2 = tid >> 5, i = tid & 31;
            const float kcv = (m2 == mech) ? sq[32 + i]
                : __hip_atomic_load(&kc_g[m2 * 32 + i], __ATOMIC_RELAXED, __HIP_MEMORY_SCOPE_AGENT);
            float p = sq[i] * kcv;
            p += __shfl_down(p, 16); p += __shfl_down(p, 8); p += __shfl_down(p, 4);
            p += __shfl_down(p, 2);  p += __shfl_down(p, 1);
            if (i == 0) sclog[m2] = p * inv_sdc;
        }
        __syncthreads();
        if (tid == 0) {
            float mx = sclog[0];
            #pragma unroll
            for (int mm = 1; mm < 5; ++mm) mx = fmaxf(mx, sclog[mm]);
            float e[5], ssum = 0.f;
            #pragma unroll
            for (int mm = 0; mm < 5; ++mm) { e[mm] = __expf(sclog[mm] - mx); ssum += e[mm]; }
            const float inv = 1.f / ssum;
            #pragma unroll
            for (int mm = 0; mm < 5; ++mm) scat[mm] = e[mm] * inv;
        }
        __syncthreads();
        // ---- h2 = h1 + mask * (cattn @ vc); emit hidden row slice
        if (tid < 128) {
            float hv = sh[tid];
            if (active) {
                float d = 0.f;
                #pragma unroll
                for (int mm = 0; mm < 5; ++mm) {
                    const float v = __hip_atomic_load(&vc_g[mm * 128 + tid], __ATOMIC_RELAXED, __HIP_MEMORY_SCOPE_AGENT);
                    d += scat[mm] * v;
                }
                hv += d;
                sh[tid] = hv;
            }
            hidden[t * 640 + mech * 128 + tid] = hv;
        }
        __syncthreads();
    }
}

// ============ kernel 3: classifier ============
__global__ __launch_bounds__(256) void cls_kernel(
    const float* __restrict__ hidden, const float* __restrict__ Wcls,
    const float* __restrict__ bcls, float* __restrict__ out)
{
    const int t = blockIdx.x * 256 + threadIdx.x;
    if (t >= T_LEN) return;
    float a0 = bcls[0], a1 = bcls[1];
    for (int d = 0; d < 640; ++d) {
        const float h = hidden[t * 640 + d];
        a0 += h * Wcls[d * 2 + 0];
        a1 += h * Wcls[d * 2 + 1];
    }
    out[t * 2 + 0] = a0;
    out[t * 2 + 1] = a1;
}

extern "C" void kernel_launch(void* const* d_in, const int* in_sizes, int n_in,
                              void* d_out, int out_size, void* d_ws, size_t ws_size,
                              hipStream_t stream)
{
    (void)in_sizes; (void)n_in; (void)out_size; (void)ws_size;
    const float* bert  = (const float*)d_in[0];
    const int*   uidx  = (const int*)d_in[1];
    const int*   pidx  = (const int*)d_in[2];
    const float* disg  = (const float*)d_in[3];
    const float* udisg = (const float*)d_in[4];
    const float* utab  = (const float*)d_in[5];
    const float* ptab  = (const float*)d_in[6];
    const float* Wk0 = (const float*)d_in[7],  *Wv0 = (const float*)d_in[8];
    const float* Wk1 = (const float*)d_in[9],  *Wv1 = (const float*)d_in[10];
    const float* Wk2 = (const float*)d_in[11], *Wv2 = (const float*)d_in[12];
    const float* Wk3 = (const float*)d_in[13], *Wv3 = (const float*)d_in[14];
    const float* Wk4 = (const float*)d_in[15], *Wv4 = (const float*)d_in[16];
    const float* Wq   = (const float*)d_in[17];
    const float* Wih  = (const float*)d_in[18];
    const float* Whh  = (const float*)d_in[19];
    const float* bl   = (const float*)d_in[20];
    const float* Wqc  = (const float*)d_in[21];
    const float* Wkc  = (const float*)d_in[22];
    const float* Wvc  = (const float*)d_in[23];
    const float* Wcls = (const float*)d_in[24];
    const float* bcls = (const float*)d_in[25];

    char* ws = (char*)d_ws;
    unsigned* bar  = (unsigned*)ws;
    float* null_g  = (float*)(ws + 0x100);
    float* kc_g    = (float*)(ws + 0x200);
    float* vc_g    = (float*)(ws + 0x600);
    float* keys    = (float*)(ws + 0x1000);
    float* vals    = (float*)(ws + 0x1000 + 786432);
    float* hidden  = (float*)(ws + 0x1000 + 2 * 786432);

    hipMemsetAsync(d_ws, 0, 256, stream);   // zero barrier counter

    hipLaunchKernelGGL(precompute_kv, dim3(T_LEN), dim3(128), 0, stream,
        bert, uidx, pidx, disg, udisg, utab, ptab,
        Wk0, Wv0, Wk1, Wv1, Wk2, Wv2, Wk3, Wv3, Wk4, Wv4, keys, vals);

    const int smem_bytes = SMEM_FLOATS * 4;   // 136832 B < 160 KiB
    (void)hipFuncSetAttribute((const void*)rim_scan,
                              hipFuncAttributeMaxDynamicSharedMemorySize, smem_bytes);
    hipLaunchKernelGGL(rim_scan, dim3(5), dim3(512), smem_bytes, stream,
        Wq, Wih, Whh, bl, Wqc, Wkc, Wvc, keys, vals, hidden, bar, null_g, kc_g, vc_g);

    hipLaunchKernelGGL(cls_kernel, dim3(2), dim3(256), 0, stream,
        hidden, Wcls, bcls, (float*)d_out);
}

// Round 2
// 6727.916 us; speedup vs baseline: 1.5152x; 1.5152x over previous
//
#include <hip/hip_runtime.h>
#include <math.h>

#define T_LEN 512

// ---------------- workspace layout (bytes) ----------------
// 0x0000 : unsigned barrier counter (memset 0 each launch)
// 0x0100 : float null_attn[5]
// 0x0200 : float kc_g[5*32]
// 0x0600 : float vc_g[5*128]
// 0x1000 : float keys[512*6*64]
// 0x1000+0xC0000 : float vals[512*6*64]
// 0x1000+2*0xC0000 : float hidden[512*640]

#define AGT __HIP_MEMORY_SCOPE_AGENT

// ============ kernel 1: key/value projections (parallel) ============
__global__ __launch_bounds__(128) void precompute_kv(
    const float* __restrict__ bert, const int* __restrict__ uidx, const int* __restrict__ pidx,
    const float* __restrict__ disg, const float* __restrict__ udisg,
    const float* __restrict__ utab, const float* __restrict__ ptab,
    const float* __restrict__ Wk0, const float* __restrict__ Wv0,
    const float* __restrict__ Wk1, const float* __restrict__ Wv1,
    const float* __restrict__ Wk2, const float* __restrict__ Wv2,
    const float* __restrict__ Wk3, const float* __restrict__ Wv3,
    const float* __restrict__ Wk4, const float* __restrict__ Wv4,
    float* __restrict__ keys, float* __restrict__ vals)
{
    __shared__ float x[768 + 50 + 20 + 2 + 2];
    const int t = blockIdx.x, tid = threadIdx.x;
    for (int i = tid; i < 768; i += 128) x[i] = bert[t * 768 + i];
    const int u = uidx[t], p = pidx[t];
    for (int i = tid; i < 50; i += 128) x[768 + i] = utab[u * 50 + i];
    for (int i = tid; i < 20; i += 128) x[818 + i] = ptab[p * 20 + i];
    if (tid < 2) x[838 + tid] = disg[t * 2 + tid];
    if (tid >= 2 && tid < 4) x[840 + (tid - 2)] = udisg[t * 2 + (tid - 2)];
    __syncthreads();
    const int j = tid & 63, isv = tid >> 6;
    float* outb = (isv ? vals : keys) + t * 384;
    {   const float* W = isv ? Wv0 : Wk0; float a = 0.f;
        for (int i = 0; i < 768; ++i) a += x[i] * W[i * 64 + j];
        outb[0 * 64 + j] = a; }
    {   const float* W = isv ? Wv1 : Wk1; float a = 0.f;
        for (int i = 0; i < 50; ++i) a += x[768 + i] * W[i * 64 + j];
        outb[1 * 64 + j] = a; }
    {   const float* W = isv ? Wv2 : Wk2; float a = 0.f;
        for (int i = 0; i < 20; ++i) a += x[818 + i] * W[i * 64 + j];
        outb[2 * 64 + j] = a; }
    {   const float* W = isv ? Wv3 : Wk3;
        outb[3 * 64 + j] = x[838] * W[j] + x[839] * W[64 + j]; }
    {   const float* W = isv ? Wv4 : Wk4;
        outb[4 * 64 + j] = x[840] * W[j] + x[841] * W[64 + j]; }
    outb[5 * 64 + j] = 0.f;   // null key/value row
}

// ============ kernel 2: the sequential RIM scan ============
// 5 blocks (one/mechanism) x 1024 threads (16 waves).
// Weights: Wq/Wqc/Wkc/Wvc/b in LDS (~131 KB); Whh 64 f + Wih 32 f per thread
// in VGPRs (2 threads per gate output -> 96 weight regs, fits 128-VGPR cap).
// Cross-block: relaxed agent atomics only (write-through to LLC); ordering via
// explicit s_waitcnt vmcnt(0) before relaxed counter add. No buffer_inv/wbl2.
// Arrivals per step: A=+1/block (tid0), B=+5/block (per publishing wave) -> 30/step.

#define SMEM_FLOATS 36112

__global__ __launch_bounds__(1024, 4) void rim_scan(
    const float* __restrict__ Wq, const float* __restrict__ Wih, const float* __restrict__ Whh,
    const float* __restrict__ b_lstm, const float* __restrict__ Wqc, const float* __restrict__ Wkc,
    const float* __restrict__ Wvc,
    const float* __restrict__ keys, const float* __restrict__ vals,
    float* __restrict__ hidden,
    unsigned* __restrict__ bar, float* __restrict__ null_g,
    float* __restrict__ kc_g, float* __restrict__ vc_g)
{
    extern __shared__ float sm[];
    float* sWq  = sm;            // 8192  : Wq[m]  [128][64]
    float* sWqc = sm + 8192;     // 4096  : Wqc[m] [128][32]
    float* sWkc = sm + 12288;    // 4096  : Wkc[m] [128][32]
    float* sWvc = sm + 16384;    // 16384 : Wvc[m] [128][128]
    float* sb   = sm + 32768;    // 512
    float* skey = sm + 33280;    // 2*384 key double-buffer
    float* sval = sm + 34048;    // 2*384 val double-buffer
    float* sqp  = sm + 34816;    // 256  q partials (4 segs x 64)
    float* sq   = sm + 35072;    // 64   qc[0:32] | kc-local[32:64]
    float* sg   = sm + 35136;    // 512  gates
    float* sh   = sm + 35648;    // 128  h state
    float* shn  = sm + 35776;    // 128  h_new candidate
    float* sinp = sm + 35904;    // 64
    float* svc  = sm + 35968;    // 128  own-mech vc
    float* slog = sm + 36096;    // 8    logits (attn then ctx)
    float* snull= sm + 36104;    // 8

    const int mech = blockIdx.x, tid = threadIdx.x;
    const int lane = tid & 63, wv = tid >> 6;
    const int g = tid >> 1, shalf = tid & 1;   // gate output / inner-half

    // ---- stage weights
    for (int i = tid; i < 8192;  i += 1024) sWq[i]  = Wq[mech * 8192 + i];
    for (int i = tid; i < 4096;  i += 1024) sWqc[i] = Wqc[mech * 4096 + i];
    for (int i = tid; i < 4096;  i += 1024) sWkc[i] = Wkc[mech * 4096 + i];
    for (int i = tid; i < 16384; i += 1024) sWvc[i] = Wvc[mech * 16384 + i];
    if (tid < 512) sb[tid] = b_lstm[mech * 512 + tid];
    if (tid < 384) { skey[tid] = keys[tid]; sval[tid] = vals[tid]; }  // prime t=0
    if (tid < 128) sh[tid] = 0.f;
    float c_reg = 0.f;
    float whhr[64], wihr[32];
    #pragma unroll
    for (int il = 0; il < 64; ++il) whhr[il] = Whh[mech * 65536 + (shalf * 64 + il) * 512 + g];
    #pragma unroll
    for (int il = 0; il < 32; ++il) wihr[il] = Wih[mech * 32768 + (shalf * 32 + il) * 512 + g];
    __syncthreads();

    #pragma unroll 1
    for (int t = 0; t < T_LEN; ++t) {
        const float* kb = skey + (t & 1) * 384;
        const float* vb = sval + (t & 1) * 384;

        // ---- S0: q partials (waves 0-3) + Whh.h part (all threads)
        if (wv < 4) {
            float acc = 0.f;
            const float*  wq  = sWq + (wv * 32) * 64 + lane;
            const float4* hb4 = (const float4*)(sh + wv * 32);
            #pragma unroll
            for (int q4 = 0; q4 < 8; ++q4) {
                float4 h4 = hb4[q4];
                acc += h4.x * wq[(4*q4  )*64] + h4.y * wq[(4*q4+1)*64]
                     + h4.z * wq[(4*q4+2)*64] + h4.w * wq[(4*q4+3)*64];
            }
            sqp[wv * 64 + lane] = acc;
        }
        float hh = 0.f;
        {
            const float4* sh4 = (const float4*)(sh + shalf * 64);
            #pragma unroll
            for (int q4 = 0; q4 < 16; ++q4) {
                float4 h4 = sh4[q4];
                hh += h4.x*whhr[4*q4] + h4.y*whhr[4*q4+1] + h4.z*whhr[4*q4+2] + h4.w*whhr[4*q4+3];
            }
        }
        __syncthreads();

        // ---- S2: attn logits over 6 keys (waves 0-5)
        if (wv < 6) {
            float qj = sqp[lane] + sqp[64 + lane] + sqp[128 + lane] + sqp[192 + lane];
            float p = qj * kb[wv * 64 + lane];
            p += __shfl_down(p, 32); p += __shfl_down(p, 16); p += __shfl_down(p, 8);
            p += __shfl_down(p, 4);  p += __shfl_down(p, 2);  p += __shfl_down(p, 1);
            if (lane == 0) slog[wv] = p * 0.125f;
        }
        __syncthreads();

        // ---- S4: per-thread softmax + inp (wave 0); tid0 publishes null, arrives A
        if (tid < 64) {
            float l0=slog[0],l1=slog[1],l2=slog[2],l3=slog[3],l4=slog[4],l5=slog[5];
            float mx = fmaxf(fmaxf(fmaxf(l0,l1),fmaxf(l2,l3)),fmaxf(l4,l5));
            float e0=__expf(l0-mx),e1=__expf(l1-mx),e2=__expf(l2-mx),
                  e3=__expf(l3-mx),e4=__expf(l4-mx),e5=__expf(l5-mx);
            float inv = 1.f / (e0+e1+e2+e3+e4+e5);
            float a = (e0*vb[tid] + e1*vb[64+tid] + e2*vb[128+tid]
                     + e3*vb[192+tid] + e4*vb[256+tid] + e5*vb[320+tid]) * inv;
            sinp[tid] = a;
            if (tid == 0) {
                __hip_atomic_store(&null_g[mech], e5 * inv, __ATOMIC_RELAXED, AGT);
                asm volatile("s_waitcnt vmcnt(0)" ::: "memory");
                __hip_atomic_fetch_add(bar, 1u, __ATOMIC_RELAXED, AGT);
            }
        }
        __syncthreads();

        // ---- S5: gates (2 threads/output, weights in regs)
        {
            float gate = hh;
            const float4* si4 = (const float4*)(sinp + shalf * 32);
            #pragma unroll
            for (int q4 = 0; q4 < 8; ++q4) {
                float4 v = si4[q4];
                gate += v.x*wihr[4*q4] + v.y*wihr[4*q4+1] + v.z*wihr[4*q4+2] + v.w*wihr[4*q4+3];
            }
            gate += __shfl_down(gate, 1);
            if (!shalf) sg[g] = gate + sb[g];
        }
        __syncthreads();

        // ---- S6: LSTM candidate; tid0 completes barrier A
        float cn = 0.f;
        if (tid < 128) {
            float gi = sg[tid], gf = sg[128+tid], gg = sg[256+tid], go = sg[384+tid];
            float si = 1.f/(1.f+__expf(-gi)), sf = 1.f/(1.f+__expf(-gf)), so = 1.f/(1.f+__expf(-go));
            cn = sf * c_reg + si * tanhf(gg);
            shn[tid] = so * tanhf(cn);
        }
        if (tid == 0) {
            const unsigned tgt = 30u * (unsigned)t + 5u;
            while (__hip_atomic_load(bar, __ATOMIC_RELAXED, AGT) < tgt)
                __builtin_amdgcn_s_sleep(1);
            asm volatile("" ::: "memory");
            #pragma unroll
            for (int mm = 0; mm < 5; ++mm)
                snull[mm] = __hip_atomic_load(&null_g[mm], __ATOMIC_RELAXED, AGT);
        }
        __syncthreads();

        // ---- mask (all threads), then S8 role-split matvecs on h1
        int rank = 0;
        {
            const float myn = snull[mech];
            #pragma unroll
            for (int mm = 0; mm < 5; ++mm) {
                const float o = snull[mm];
                rank += (o < myn || (o == myn && mm < mech)) ? 1 : 0;
            }
        }
        const bool active = (rank < 3);
        if (tid < 128 && active) c_reg = cn;
        const float* h1 = active ? shn : sh;

        if (wv < 2) {
            // wave0: qc, wave1: kc  (col = lane&31, inner half = lane>>5)
            const float* W = (wv == 0) ? sWqc : sWkc;
            const int col = lane & 31, ih = lane >> 5;
            float acc = 0.f;
            const float*  wp = W + (ih * 64) * 32 + col;
            const float4* hb = (const float4*)(h1 + ih * 64);
            #pragma unroll
            for (int q4 = 0; q4 < 16; ++q4) {
                float4 h4 = hb[q4];
                acc += h4.x*wp[(4*q4  )*32] + h4.y*wp[(4*q4+1)*32]
                     + h4.z*wp[(4*q4+2)*32] + h4.w*wp[(4*q4+3)*32];
            }
            acc += __shfl_down(acc, 32);
            if (lane < 32) {
                if (wv == 0) sq[col] = acc;
                else {
                    sq[32 + col] = acc;
                    __hip_atomic_store(&kc_g[mech * 32 + col], acc, __ATOMIC_RELAXED, AGT);
                }
            }
            if (wv == 1 && lane == 0) {
                asm volatile("s_waitcnt vmcnt(0)" ::: "memory");
                __hip_atomic_fetch_add(bar, 1u, __ATOMIC_RELAXED, AGT);
            }
        } else if (wv < 6) {
            // waves 2-5: vc (2 threads/output)
            const int idx = tid - 128, out = idx >> 1, s2 = idx & 1;
            float acc = 0.f;
            const float*  wp = sWvc + (s2 * 64) * 128 + out;
            const float4* hb = (const float4*)(h1 + s2 * 64);
            #pragma unroll
            for (int q4 = 0; q4 < 16; ++q4) {
                float4 h4 = hb[q4];
                acc += h4.x*wp[(4*q4  )*128] + h4.y*wp[(4*q4+1)*128]
                     + h4.z*wp[(4*q4+2)*128] + h4.w*wp[(4*q4+3)*128];
            }
            acc += __shfl_down(acc, 1);
            if (!s2) {
                svc[out] = acc;
                __hip_atomic_store(&vc_g[mech * 128 + out], acc, __ATOMIC_RELAXED, AGT);
            }
            if (lane == 0) {
                asm volatile("s_waitcnt vmcnt(0)" ::: "memory");
                __hip_atomic_fetch_add(bar, 1u, __ATOMIC_RELAXED, AGT);
            }
        } else if (wv >= 8) {
            // waves 8-15: prefetch t+1 keys/vals into the other buffer
            const int idx = tid - 512;
            const int tn = (t < T_LEN - 1) ? t + 1 : T_LEN - 1;
            const float* kr = keys + tn * 384;
            const float* vr = vals + tn * 384;
            float* kb2 = skey + ((t + 1) & 1) * 384;
            float* vb2 = sval + ((t + 1) & 1) * 384;
            if (idx < 384) kb2[idx] = kr[idx]; else vb2[idx - 384] = vr[idx - 384];
            if (idx < 256) vb2[idx + 128] = vr[idx + 128];
        }
        if (tid == 0) {
            const unsigned tgt = 30u * (unsigned)t + 30u;
            while (__hip_atomic_load(bar, __ATOMIC_RELAXED, AGT) < tgt)
                __builtin_amdgcn_s_sleep(1);
            asm volatile("" ::: "memory");
        }
        __syncthreads();

        // ---- S9: context-attn logits (waves 0-4, lanes 0-31)
        if (wv < 5 && lane < 32) {
            float kcv = (wv == mech) ? sq[32 + lane]
                : __hip_atomic_load(&kc_g[wv * 32 + lane], __ATOMIC_RELAXED, AGT);
            float p = sq[lane] * kcv;
            p += __shfl_down(p, 16); p += __shfl_down(p, 8); p += __shfl_down(p, 4);
            p += __shfl_down(p, 2);  p += __shfl_down(p, 1);
            if (lane == 0) slog[wv] = p * 0.17677669529663687f;
        }
        __syncthreads();

        // ---- S11: per-thread ctx softmax, h2, state + hidden store
        if (tid < 128) {
            float l0=slog[0],l1=slog[1],l2=slog[2],l3=slog[3],l4=slog[4];
            float mx = fmaxf(fmaxf(fmaxf(l0,l1),fmaxf(l2,l3)),l4);
            float e0=__expf(l0-mx),e1=__expf(l1-mx),e2=__expf(l2-mx),e3=__expf(l3-mx),e4=__expf(l4-mx);
            float inv = 1.f / (e0+e1+e2+e3+e4);
            float hv = h1[tid];
            if (active) {
                float v0 = (0==mech)? svc[tid] : __hip_atomic_load(&vc_g[0*128+tid], __ATOMIC_RELAXED, AGT);
                float v1 = (1==mech)? svc[tid] : __hip_atomic_load(&vc_g[1*128+tid], __ATOMIC_RELAXED, AGT);
                float v2 = (2==mech)? svc[tid] : __hip_atomic_load(&vc_g[2*128+tid], __ATOMIC_RELAXED, AGT);
                float v3 = (3==mech)? svc[tid] : __hip_atomic_load(&vc_g[3*128+tid], __ATOMIC_RELAXED, AGT);
                float v4 = (4==mech)? svc[tid] : __hip_atomic_load(&vc_g[4*128+tid], __ATOMIC_RELAXED, AGT);
                hv += (e0*v0 + e1*v1 + e2*v2 + e3*v3 + e4*v4) * inv;
            }
            sh[tid] = hv;
            hidden[t * 640 + mech * 128 + tid] = hv;
        }
        __syncthreads();
    }
}

// ============ kernel 3: classifier ============
__global__ __launch_bounds__(256) void cls_kernel(
    const float* __restrict__ hidden, const float* __restrict__ Wcls,
    const float* __restrict__ bcls, float* __restrict__ out)
{
    const int t = blockIdx.x * 256 + threadIdx.x;
    if (t >= T_LEN) return;
    float a0 = bcls[0], a1 = bcls[1];
    for (int d = 0; d < 640; ++d) {
        const float h = hidden[t * 640 + d];
        a0 += h * Wcls[d * 2 + 0];
        a1 += h * Wcls[d * 2 + 1];
    }
    out[t * 2 + 0] = a0;
    out[t * 2 + 1] = a1;
}

extern "C" void kernel_launch(void* const* d_in, const int* in_sizes, int n_in,
                              void* d_out, int out_size, void* d_ws, size_t ws_size,
                              hipStream_t stream)
{
    (void)in_sizes; (void)n_in; (void)out_size; (void)ws_size;
    const float* bert  = (const float*)d_in[0];
    const int*   uidx  = (const int*)d_in[1];
    const int*   pidx  = (const int*)d_in[2];
    const float* disg  = (const float*)d_in[3];
    const float* udisg = (const float*)d_in[4];
    const float* utab  = (const float*)d_in[5];
    const float* ptab  = (const float*)d_in[6];
    const float* Wk0 = (const float*)d_in[7],  *Wv0 = (const float*)d_in[8];
    const float* Wk1 = (const float*)d_in[9],  *Wv1 = (const float*)d_in[10];
    const float* Wk2 = (const float*)d_in[11], *Wv2 = (const float*)d_in[12];
    const float* Wk3 = (const float*)d_in[13], *Wv3 = (const float*)d_in[14];
    const float* Wk4 = (const float*)d_in[15], *Wv4 = (const float*)d_in[16];
    const float* Wq   = (const float*)d_in[17];
    const float* Wih  = (const float*)d_in[18];
    const float* Whh  = (const float*)d_in[19];
    const float* bl   = (const float*)d_in[20];
    const float* Wqc  = (const float*)d_in[21];
    const float* Wkc  = (const float*)d_in[22];
    const float* Wvc  = (const float*)d_in[23];
    const float* Wcls = (const float*)d_in[24];
    const float* bcls = (const float*)d_in[25];

    char* ws = (char*)d_ws;
    unsigned* bar  = (unsigned*)ws;
    float* null_g  = (float*)(ws + 0x100);
    float* kc_g    = (float*)(ws + 0x200);
    float* vc_g    = (float*)(ws + 0x600);
    float* keys    = (float*)(ws + 0x1000);
    float* vals    = (float*)(ws + 0x1000 + 786432);
    float* hidden  = (float*)(ws + 0x1000 + 2 * 786432);

    hipMemsetAsync(d_ws, 0, 256, stream);   // zero barrier counter

    hipLaunchKernelGGL(precompute_kv, dim3(T_LEN), dim3(128), 0, stream,
        bert, uidx, pidx, disg, udisg, utab, ptab,
        Wk0, Wv0, Wk1, Wv1, Wk2, Wv2, Wk3, Wv3, Wk4, Wv4, keys, vals);

    const int smem_bytes = SMEM_FLOATS * 4;   // 144448 B < 160 KiB
    (void)hipFuncSetAttribute((const void*)rim_scan,
                              hipFuncAttributeMaxDynamicSharedMemorySize, smem_bytes);
    hipLaunchKernelGGL(rim_scan, dim3(5), dim3(1024), smem_bytes, stream,
        Wq, Wih, Whh, bl, Wqc, Wkc, Wvc, keys, vals, hidden, bar, null_g, kc_g, vc_g);

    hipLaunchKernelGGL(cls_kernel, dim3(2), dim3(256), 0, stream,
        hidden, Wcls, bcls, (float*)d_out);
}

// Round 3
// 6390.981 us; speedup vs baseline: 1.5951x; 1.0527x over previous
//
#include <hip/hip_runtime.h>
#include <math.h>

#define T_LEN 512
#define AGT __HIP_MEMORY_SCOPE_AGENT

// ---------------- workspace layout (bytes) ----------------
// 0x0000 : unsigned barrier counter (memset 0 each launch)
// 0x0100 : float null_g[2][8]        (parity-buffered null_attn)
// 0x0200 : float kcg[2][5][2][32]    (par, mech, variant, DC)
// 0x0C00 : float vcg[2][5][2][128]
// 0x4000 : float keys[512*6*64]
// 0x4000+0xC0000 : float vals[512*6*64]
// 0x4000+2*0xC0000 : float hidden[512*640]

__device__ __forceinline__ float tanh_f(float x) {
    const float e = __expf(2.f * x);
    return 1.f - 2.f / (e + 1.f);
}

// ============ kernel 1: key/value projections (parallel) ============
__global__ __launch_bounds__(128) void precompute_kv(
    const float* __restrict__ bert, const int* __restrict__ uidx, const int* __restrict__ pidx,
    const float* __restrict__ disg, const float* __restrict__ udisg,
    const float* __restrict__ utab, const float* __restrict__ ptab,
    const float* __restrict__ Wk0, const float* __restrict__ Wv0,
    const float* __restrict__ Wk1, const float* __restrict__ Wv1,
    const float* __restrict__ Wk2, const float* __restrict__ Wv2,
    const float* __restrict__ Wk3, const float* __restrict__ Wv3,
    const float* __restrict__ Wk4, const float* __restrict__ Wv4,
    float* __restrict__ keys, float* __restrict__ vals)
{
    __shared__ float x[768 + 50 + 20 + 2 + 2];
    const int t = blockIdx.x, tid = threadIdx.x;
    for (int i = tid; i < 768; i += 128) x[i] = bert[t * 768 + i];
    const int u = uidx[t], p = pidx[t];
    for (int i = tid; i < 50; i += 128) x[768 + i] = utab[u * 50 + i];
    for (int i = tid; i < 20; i += 128) x[818 + i] = ptab[p * 20 + i];
    if (tid < 2) x[838 + tid] = disg[t * 2 + tid];
    if (tid >= 2 && tid < 4) x[840 + (tid - 2)] = udisg[t * 2 + (tid - 2)];
    __syncthreads();
    const int j = tid & 63, isv = tid >> 6;
    float* outb = (isv ? vals : keys) + t * 384;
    {   const float* W = isv ? Wv0 : Wk0; float a = 0.f;
        for (int i = 0; i < 768; ++i) a += x[i] * W[i * 64 + j];
        outb[0 * 64 + j] = a; }
    {   const float* W = isv ? Wv1 : Wk1; float a = 0.f;
        for (int i = 0; i < 50; ++i) a += x[768 + i] * W[i * 64 + j];
        outb[1 * 64 + j] = a; }
    {   const float* W = isv ? Wv2 : Wk2; float a = 0.f;
        for (int i = 0; i < 20; ++i) a += x[818 + i] * W[i * 64 + j];
        outb[2 * 64 + j] = a; }
    {   const float* W = isv ? Wv3 : Wk3;
        outb[3 * 64 + j] = x[838] * W[j] + x[839] * W[64 + j]; }
    {   const float* W = isv ? Wv4 : Wk4;
        outb[4 * 64 + j] = x[840] * W[j] + x[841] * W[64 + j]; }
    outb[5 * 64 + j] = 0.f;   // null key/value row
}

// ============ kernel 2: the sequential RIM scan ============
// 5 blocks x 512 threads (8 waves). __launch_bounds__(512,1): 8 waves/CU ->
// 2 waves/SIMD -> 256-VGPR cap (round-2 showed arg2 == blocks/CU on this
// compiler; either interpretation gives >=256 here). Gate weights 192 f/thread
// in VGPRs. Wq/Wqc/Wkc/Wvc transposed + XOR-swizzled f4 chunks in LDS.
// ONE device barrier/step: both h-variants of kc/vc published speculatively;
// consumers select per-mech variant after the mask is known.

#define SMEM_FLOATS 36176

__global__ __launch_bounds__(512, 1) void rim_scan(
    const float* __restrict__ Wq, const float* __restrict__ Wih, const float* __restrict__ Whh,
    const float* __restrict__ b_lstm, const float* __restrict__ Wqc, const float* __restrict__ Wkc,
    const float* __restrict__ Wvc,
    const float* __restrict__ keys, const float* __restrict__ vals,
    float* __restrict__ hidden,
    unsigned* __restrict__ bar, float* __restrict__ null_g,
    float* __restrict__ kcg, float* __restrict__ vcg)
{
    extern __shared__ float sm[];
    float* swq  = sm;            // 8192  Wq_T  [64 out][128 K] swizzled
    float* swqc = sm + 8192;     // 4096  Wqc_T [32][128]
    float* swkc = sm + 12288;    // 4096  Wkc_T [32][128]
    float* swvc = sm + 16384;    // 16384 Wvc_T [128][128]
    float* skey = sm + 32768;    // 2*384 key double-buffer
    float* sval = sm + 33536;    // 2*384 val double-buffer
    float* sqp  = sm + 34304;    // 512   q partials (8 segs x 64)
    float* sg   = sm + 34816;    // 512   gates
    float* sh   = sm + 35328;    // 128   h state
    float* shn  = sm + 35456;    // 128   h_new candidate
    float* sop  = sm + 35584;    // 192   gate operand: [inp(64) | h(128)]
    float* qcl  = sm + 35776;    // 64    qc[var][32]
    float* kcl  = sm + 35840;    // 64    kc[var][32]
    float* vcl  = sm + 35904;    // 256   vc[var][128]
    float* slog = sm + 36160;    // 8     ctx logits
    float* snull= sm + 36168;    // 8

    const int mech = blockIdx.x, tid = threadIdx.x;
    const int lane = tid & 63, wv = tid >> 6;

    // ---- stage transposed+swizzled weights into LDS
    for (int idx = tid; idx < 8192; idx += 512) {
        const int i = idx >> 6, j = idx & 63;          // Wq[m][i][j]
        swq[j * 128 + ((((i >> 2) ^ (j & 7)) << 2) | (i & 3))] = Wq[mech * 8192 + idx];
    }
    for (int idx = tid; idx < 4096; idx += 512) {
        const int i = idx >> 5, c = idx & 31;
        const int pos = c * 128 + ((((i >> 2) ^ (c & 7)) << 2) | (i & 3));
        swqc[pos] = Wqc[mech * 4096 + idx];
        swkc[pos] = Wkc[mech * 4096 + idx];
    }
    for (int idx = tid; idx < 16384; idx += 512) {
        const int i = idx >> 7, o = idx & 127;
        swvc[o * 128 + ((((i >> 2) ^ (o & 7)) << 2) | (i & 3))] = Wvc[mech * 16384 + idx];
    }
    if (tid < 384) { skey[tid] = keys[tid]; sval[tid] = vals[tid]; }  // prime t=0
    if (tid < 192) sop[tid] = 0.f;
    if (tid < 128) { sh[tid] = 0.f; shn[tid] = 0.f; }

    // ---- gate weights in registers: pair = output column pair, s = K-half
    const int pair = tid >> 1, s = tid & 1;
    const int o0 = pair, o1 = pair + 256;
    float wA[96], wB[96];
    if (s == 0) {
        #pragma unroll
        for (int k = 0; k < 64; ++k) {
            wA[k] = Wih[mech * 32768 + k * 512 + o0];
            wB[k] = Wih[mech * 32768 + k * 512 + o1];
        }
        #pragma unroll
        for (int k = 0; k < 32; ++k) {
            wA[64 + k] = Whh[mech * 65536 + k * 512 + o0];
            wB[64 + k] = Whh[mech * 65536 + k * 512 + o1];
        }
    } else {
        #pragma unroll
        for (int k = 0; k < 96; ++k) {
            wA[k] = Whh[mech * 65536 + (32 + k) * 512 + o0];
            wB[k] = Whh[mech * 65536 + (32 + k) * 512 + o1];
        }
    }
    const float b0v = (s == 0) ? b_lstm[mech * 512 + o0] : 0.f;
    const float b1v = (s == 0) ? b_lstm[mech * 512 + o1] : 0.f;
    float c_reg = 0.f, cn = 0.f;
    __syncthreads();

    #pragma unroll 1
    for (int t = 0; t < T_LEN; ++t) {
        const int par = t & 1;
        const float* kb = skey + par * 384;
        const float* vb = sval + par * 384;

        // qc/kc matvec (waves 1-2), both-variant helper
        auto qckc = [&](const float* hsrc, int var) {
            const int idx2 = tid - 64, cc = idx2 >> 1, s2 = idx2 & 1;
            const float* wrow = (cc < 32) ? (swqc + cc * 128) : (swkc + (cc - 32) * 128);
            const int rx = cc & 7;
            const float4* h4 = (const float4*)(hsrc + s2 * 64);
            float p = 0.f;
            #pragma unroll
            for (int j = 0; j < 16; ++j) {
                const float4 w = *(const float4*)(wrow + (((s2 * 16 + j) ^ rx) << 2));
                const float4 hv = h4[j];
                p += w.x * hv.x + w.y * hv.y + w.z * hv.z + w.w * hv.w;
            }
            p += __shfl_xor(p, 1);
            if (s2 == 0) {
                if (cc < 32) qcl[var * 32 + cc] = p;
                else {
                    kcl[var * 32 + (cc - 32)] = p;
                    __hip_atomic_store(&kcg[((par * 5 + mech) * 2 + var) * 32 + (cc - 32)],
                                       p, __ATOMIC_RELAXED, AGT);
                }
            }
            if (wv == 2 && lane == 0) {
                asm volatile("s_waitcnt vmcnt(0)" ::: "memory");
                __hip_atomic_fetch_add(bar, 1u, __ATOMIC_RELAXED, AGT);
            }
        };
        // vc matvec (waves 3-6), both-variant helper
        auto vcf = [&](const float* hsrc, int var) {
            const int idx3 = tid - 192, o = idx3 >> 1, s3 = idx3 & 1;
            const float* wrow = swvc + o * 128;
            const int rx = o & 7;
            const float4* h4 = (const float4*)(hsrc + s3 * 64);
            float p = 0.f;
            #pragma unroll
            for (int j = 0; j < 16; ++j) {
                const float4 w = *(const float4*)(wrow + (((s3 * 16 + j) ^ rx) << 2));
                const float4 hv = h4[j];
                p += w.x * hv.x + w.y * hv.y + w.z * hv.z + w.w * hv.w;
            }
            p += __shfl_xor(p, 1);
            if (s3 == 0) {
                vcl[var * 128 + o] = p;
                __hip_atomic_store(&vcg[((par * 5 + mech) * 2 + var) * 128 + o],
                                   p, __ATOMIC_RELAXED, AGT);
            }
            if (lane == 0) {
                asm volatile("s_waitcnt vmcnt(0)" ::: "memory");
                __hip_atomic_fetch_add(bar, 1u, __ATOMIC_RELAXED, AGT);
            }
        };

        // ---- S0: q partials (all 8 waves; seg = wave)
        {
            const int out = lane, rx = out & 7;
            const float* wrow = swq + out * 128;
            const float4* h4 = (const float4*)(sh + wv * 16);
            float acc = 0.f;
            #pragma unroll
            for (int j = 0; j < 4; ++j) {
                const float4 w = *(const float4*)(wrow + (((wv * 4 + j) ^ rx) << 2));
                const float4 hv = h4[j];
                acc += w.x * hv.x + w.y * hv.y + w.z * hv.z + w.w * hv.w;
            }
            sqp[wv * 64 + out] = acc;
        }
        __syncthreads();

        // ---- S1: wave0 attn+softmax+inp+null | w1-2 qc0/kc0 | w3-6 vc0 | w7 prefetch
        if (wv == 0) {
            float q = 0.f;
            #pragma unroll
            for (int k = 0; k < 8; ++k) q += sqp[k * 64 + lane];
            float l[6];
            #pragma unroll
            for (int k = 0; k < 6; ++k) {
                float p = q * kb[k * 64 + lane];
                p += __shfl_down(p, 32); p += __shfl_down(p, 16); p += __shfl_down(p, 8);
                p += __shfl_down(p, 4);  p += __shfl_down(p, 2);  p += __shfl_down(p, 1);
                l[k] = __shfl(p, 0) * 0.125f;
            }
            const float mx = fmaxf(fmaxf(fmaxf(l[0], l[1]), fmaxf(l[2], l[3])), fmaxf(l[4], l[5]));
            const float e0 = __expf(l[0] - mx), e1 = __expf(l[1] - mx), e2 = __expf(l[2] - mx);
            const float e3 = __expf(l[3] - mx), e4 = __expf(l[4] - mx), e5 = __expf(l[5] - mx);
            const float inv = 1.f / (e0 + e1 + e2 + e3 + e4 + e5);
            sop[lane] = (e0 * vb[lane] + e1 * vb[64 + lane] + e2 * vb[128 + lane]
                       + e3 * vb[192 + lane] + e4 * vb[256 + lane] + e5 * vb[320 + lane]) * inv;
            if (lane == 0) {
                __hip_atomic_store(&null_g[par * 8 + mech], e5 * inv, __ATOMIC_RELAXED, AGT);
                asm volatile("s_waitcnt vmcnt(0)" ::: "memory");
                __hip_atomic_fetch_add(bar, 1u, __ATOMIC_RELAXED, AGT);
            }
        } else if (wv <= 2) {
            qckc(sh, 0);
        } else if (wv <= 6) {
            vcf(sh, 0);
        } else {
            const int tn = (t < T_LEN - 1) ? t + 1 : t;
            const int nx = (t + 1) & 1;
            const float4* kn = (const float4*)(keys + tn * 384);
            const float4* vn = (const float4*)(vals + tn * 384);
            float4* kd = (float4*)(skey + nx * 384);
            float4* vd = (float4*)(sval + nx * 384);
            #pragma unroll
            for (int rep = 0; rep < 3; ++rep) {
                const int i = rep * 64 + lane;
                if (i < 96) kd[i] = kn[i];
                else if (i < 192) vd[i - 96] = vn[i - 96];
            }
        }
        __syncthreads();

        // ---- S2: gates, weights in regs, pair-split K via shfl_xor(1)
        {
            const float4* op = (const float4*)(sop + s * 96);
            float p0 = b0v, p1 = b1v;
            #pragma unroll
            for (int q = 0; q < 24; ++q) {
                const float4 v = op[q];
                p0 += v.x * wA[4 * q] + v.y * wA[4 * q + 1] + v.z * wA[4 * q + 2] + v.w * wA[4 * q + 3];
                p1 += v.x * wB[4 * q] + v.y * wB[4 * q + 1] + v.z * wB[4 * q + 2] + v.w * wB[4 * q + 3];
            }
            const float r0 = p0 + __shfl_xor(p0, 1);
            const float r1 = p1 + __shfl_xor(p1, 1);
            if (s == 0) { sg[o0] = r0; sg[o1] = r1; }
        }
        __syncthreads();

        // ---- S3: LSTM candidate
        if (tid < 128) {
            const float gi = sg[tid], gf = sg[128 + tid], gg = sg[256 + tid], go = sg[384 + tid];
            const float si = 1.f / (1.f + __expf(-gi));
            const float sf = 1.f / (1.f + __expf(-gf));
            const float so = 1.f / (1.f + __expf(-go));
            cn = sf * c_reg + si * tanh_f(gg);
            shn[tid] = so * tanh_f(cn);
        }
        __syncthreads();

        // ---- S4: variant-1 matvecs (h_new); tid0 waits the single barrier
        if (wv >= 1 && wv <= 2) qckc(shn, 1);
        else if (wv >= 3 && wv <= 6) vcf(shn, 1);
        if (tid == 0) {
            const unsigned tgt = 55u * (unsigned)(t + 1);   // 11 arrivals/block/step
            while (__hip_atomic_load(bar, __ATOMIC_RELAXED, AGT) < tgt)
                __builtin_amdgcn_s_sleep(1);
            asm volatile("" ::: "memory");
            #pragma unroll
            for (int mm = 0; mm < 5; ++mm)
                snull[mm] = __hip_atomic_load(&null_g[par * 8 + mm], __ATOMIC_RELAXED, AGT);
        }
        __syncthreads();

        // ---- S5: ctx logits (waves 3-7) + remote vc loads (tid<128)
        int selfAct;
        {
            const float myn = snull[mech]; int r = 0;
            #pragma unroll
            for (int mm = 0; mm < 5; ++mm) {
                const float o = snull[mm];
                r += (o < myn || (o == myn && mm < mech)) ? 1 : 0;
            }
            selfAct = (r < 3) ? 1 : 0;
        }
        float v0 = 0.f, v1 = 0.f, v2 = 0.f, v3 = 0.f, v4 = 0.f;
        if (wv >= 3 && lane < 32) {
            const int m2 = wv - 3;
            const float nm = snull[m2]; int r2 = 0;
            #pragma unroll
            for (int mm = 0; mm < 5; ++mm) {
                const float o = snull[mm];
                r2 += (o < nm || (o == nm && mm < m2)) ? 1 : 0;
            }
            const int sel2 = (r2 < 3) ? 1 : 0;
            const float kcv = (m2 == mech) ? kcl[sel2 * 32 + lane]
                : __hip_atomic_load(&kcg[((par * 5 + m2) * 2 + sel2) * 32 + lane], __ATOMIC_RELAXED, AGT);
            float p = qcl[selfAct * 32 + lane] * kcv;
            p += __shfl_down(p, 16); p += __shfl_down(p, 8); p += __shfl_down(p, 4);
            p += __shfl_down(p, 2);  p += __shfl_down(p, 1);
            if (lane == 0) slog[m2] = p * 0.17677669529663687f;
        }
        if (tid < 128) {
            int sel[5];
            #pragma unroll
            for (int mm = 0; mm < 5; ++mm) {
                const float nm = snull[mm]; int rr = 0;
                #pragma unroll
                for (int m3 = 0; m3 < 5; ++m3) {
                    const float o = snull[m3];
                    rr += (o < nm || (o == nm && m3 < mm)) ? 1 : 0;
                }
                sel[mm] = (rr < 3) ? 1 : 0;
            }
            v0 = (mech == 0) ? vcl[sel[0] * 128 + tid]
               : __hip_atomic_load(&vcg[((par * 5 + 0) * 2 + sel[0]) * 128 + tid], __ATOMIC_RELAXED, AGT);
            v1 = (mech == 1) ? vcl[sel[1] * 128 + tid]
               : __hip_atomic_load(&vcg[((par * 5 + 1) * 2 + sel[1]) * 128 + tid], __ATOMIC_RELAXED, AGT);
            v2 = (mech == 2) ? vcl[sel[2] * 128 + tid]
               : __hip_atomic_load(&vcg[((par * 5 + 2) * 2 + sel[2]) * 128 + tid], __ATOMIC_RELAXED, AGT);
            v3 = (mech == 3) ? vcl[sel[3] * 128 + tid]
               : __hip_atomic_load(&vcg[((par * 5 + 3) * 2 + sel[3]) * 128 + tid], __ATOMIC_RELAXED, AGT);
            v4 = (mech == 4) ? vcl[sel[4] * 128 + tid]
               : __hip_atomic_load(&vcg[((par * 5 + 4) * 2 + sel[4]) * 128 + tid], __ATOMIC_RELAXED, AGT);
        }
        __syncthreads();

        // ---- S6: ctx softmax + h2 + state update + hidden store
        if (tid < 128) {
            const float l0 = slog[0], l1 = slog[1], l2 = slog[2], l3 = slog[3], l4 = slog[4];
            const float mx = fmaxf(fmaxf(fmaxf(l0, l1), fmaxf(l2, l3)), l4);
            const float e0 = __expf(l0 - mx), e1 = __expf(l1 - mx), e2 = __expf(l2 - mx);
            const float e3 = __expf(l3 - mx), e4 = __expf(l4 - mx);
            const float inv = 1.f / (e0 + e1 + e2 + e3 + e4);
            float hv = selfAct ? shn[tid] : sh[tid];
            if (selfAct) {
                hv += (e0 * v0 + e1 * v1 + e2 * v2 + e3 * v3 + e4 * v4) * inv;
                c_reg = cn;
            }
            sh[tid] = hv;
            sop[64 + tid] = hv;
            hidden[t * 640 + mech * 128 + tid] = hv;
        }
        __syncthreads();
    }
}

// ============ kernel 3: classifier ============
__global__ __launch_bounds__(256) void cls_kernel(
    const float* __restrict__ hidden, const float* __restrict__ Wcls,
    const float* __restrict__ bcls, float* __restrict__ out)
{
    const int t = blockIdx.x * 256 + threadIdx.x;
    if (t >= T_LEN) return;
    float a0 = bcls[0], a1 = bcls[1];
    for (int d = 0; d < 640; ++d) {
        const float h = hidden[t * 640 + d];
        a0 += h * Wcls[d * 2 + 0];
        a1 += h * Wcls[d * 2 + 1];
    }
    out[t * 2 + 0] = a0;
    out[t * 2 + 1] = a1;
}

extern "C" void kernel_launch(void* const* d_in, const int* in_sizes, int n_in,
                              void* d_out, int out_size, void* d_ws, size_t ws_size,
                              hipStream_t stream)
{
    (void)in_sizes; (void)n_in; (void)out_size; (void)ws_size;
    const float* bert  = (const float*)d_in[0];
    const int*   uidx  = (const int*)d_in[1];
    const int*   pidx  = (const int*)d_in[2];
    const float* disg  = (const float*)d_in[3];
    const float* udisg = (const float*)d_in[4];
    const float* utab  = (const float*)d_in[5];
    const float* ptab  = (const float*)d_in[6];
    const float* Wk0 = (const float*)d_in[7],  *Wv0 = (const float*)d_in[8];
    const float* Wk1 = (const float*)d_in[9],  *Wv1 = (const float*)d_in[10];
    const float* Wk2 = (const float*)d_in[11], *Wv2 = (const float*)d_in[12];
    const float* Wk3 = (const float*)d_in[13], *Wv3 = (const float*)d_in[14];
    const float* Wk4 = (const float*)d_in[15], *Wv4 = (const float*)d_in[16];
    const float* Wq   = (const float*)d_in[17];
    const float* Wih  = (const float*)d_in[18];
    const float* Whh  = (const float*)d_in[19];
    const float* bl   = (const float*)d_in[20];
    const float* Wqc  = (const float*)d_in[21];
    const float* Wkc  = (const float*)d_in[22];
    const float* Wvc  = (const float*)d_in[23];
    const float* Wcls = (const float*)d_in[24];
    const float* bcls = (const float*)d_in[25];

    char* ws = (char*)d_ws;
    unsigned* bar  = (unsigned*)ws;
    float* null_g  = (float*)(ws + 0x100);
    float* kcg     = (float*)(ws + 0x200);
    float* vcg     = (float*)(ws + 0xC00);
    float* keys    = (float*)(ws + 0x4000);
    float* vals    = (float*)(ws + 0x4000 + 786432);
    float* hidden  = (float*)(ws + 0x4000 + 2 * 786432);

    hipMemsetAsync(d_ws, 0, 256, stream);   // zero barrier counter

    hipLaunchKernelGGL(precompute_kv, dim3(T_LEN), dim3(128), 0, stream,
        bert, uidx, pidx, disg, udisg, utab, ptab,
        Wk0, Wv0, Wk1, Wv1, Wk2, Wv2, Wk3, Wv3, Wk4, Wv4, keys, vals);

    const int smem_bytes = SMEM_FLOATS * 4;   // 144704 B < 160 KiB
    (void)hipFuncSetAttribute((const void*)rim_scan,
                              hipFuncAttributeMaxDynamicSharedMemorySize, smem_bytes);
    hipLaunchKernelGGL(rim_scan, dim3(5), dim3(512), smem_bytes, stream,
        Wq, Wih, Whh, bl, Wqc, Wkc, Wvc, keys, vals, hidden, bar, null_g, kcg, vcg);

    hipLaunchKernelGGL(cls_kernel, dim3(2), dim3(256), 0, stream,
        hidden, Wcls, bcls, (float*)d_out);
}

// Round 4
// 5227.906 us; speedup vs baseline: 1.9500x; 1.2225x over previous
//
#include <hip/hip_runtime.h>
#include <math.h>

#define T_LEN 512
#define AGT __HIP_MEMORY_SCOPE_AGENT

// ---------------- workspace layout (bytes) ----------------
// 0x0000 : unsigned barrier counter (memset 0 each launch)
// 0x0100 : float null_g[2][8]        (parity-buffered null_attn)
// 0x0200 : float kcg[2][5][2][32]    (par, mech, variant, DC)
// 0x0C00 : float vcg[2][5][2][128]
// 0x4000 : float keys[512*6*64]
// 0x4000+0xC0000 : float vals[512*6*64]
// 0x4000+2*0xC0000 : float hidden[512*640]

__device__ __forceinline__ float tanh_f(float x) {
    const float e = __expf(2.f * x);
    return 1.f - 2.f / (e + 1.f);
}

// ============ kernel 1: key/value projections (parallel) ============
__global__ __launch_bounds__(128) void precompute_kv(
    const float* __restrict__ bert, const int* __restrict__ uidx, const int* __restrict__ pidx,
    const float* __restrict__ disg, const float* __restrict__ udisg,
    const float* __restrict__ utab, const float* __restrict__ ptab,
    const float* __restrict__ Wk0, const float* __restrict__ Wv0,
    const float* __restrict__ Wk1, const float* __restrict__ Wv1,
    const float* __restrict__ Wk2, const float* __restrict__ Wv2,
    const float* __restrict__ Wk3, const float* __restrict__ Wv3,
    const float* __restrict__ Wk4, const float* __restrict__ Wv4,
    float* __restrict__ keys, float* __restrict__ vals)
{
    __shared__ float x[768 + 50 + 20 + 2 + 2];
    const int t = blockIdx.x, tid = threadIdx.x;
    for (int i = tid; i < 768; i += 128) x[i] = bert[t * 768 + i];
    const int u = uidx[t], p = pidx[t];
    for (int i = tid; i < 50; i += 128) x[768 + i] = utab[u * 50 + i];
    for (int i = tid; i < 20; i += 128) x[818 + i] = ptab[p * 20 + i];
    if (tid < 2) x[838 + tid] = disg[t * 2 + tid];
    if (tid >= 2 && tid < 4) x[840 + (tid - 2)] = udisg[t * 2 + (tid - 2)];
    __syncthreads();
    const int j = tid & 63, isv = tid >> 6;
    float* outb = (isv ? vals : keys) + t * 384;
    {   const float* W = isv ? Wv0 : Wk0; float a = 0.f;
        for (int i = 0; i < 768; ++i) a += x[i] * W[i * 64 + j];
        outb[0 * 64 + j] = a; }
    {   const float* W = isv ? Wv1 : Wk1; float a = 0.f;
        for (int i = 0; i < 50; ++i) a += x[768 + i] * W[i * 64 + j];
        outb[1 * 64 + j] = a; }
    {   const float* W = isv ? Wv2 : Wk2; float a = 0.f;
        for (int i = 0; i < 20; ++i) a += x[818 + i] * W[i * 64 + j];
        outb[2 * 64 + j] = a; }
    {   const float* W = isv ? Wv3 : Wk3;
        outb[3 * 64 + j] = x[838] * W[j] + x[839] * W[64 + j]; }
    {   const float* W = isv ? Wv4 : Wk4;
        outb[4 * 64 + j] = x[840] * W[j] + x[841] * W[64 + j]; }
    outb[5 * 64 + j] = 0.f;   // null key/value row
}

// ============ kernel 2: the sequential RIM scan ============
// Grid = 40 blocks; only blockIdx.x%8==0 work (mech = bx>>3) -> with the
// empirical round-robin block->XCD mapping all 5 real blocks share XCD 0,
// making cross-block atomics local-L2 instead of cross-XCD LLC. Correctness
// does not depend on the mapping (agent-scope atomics are device-coherent).
// 512 threads; amdgpu_waves_per_eu(2,2) pins the VGPR cap at 256 (dynamic LDS
// hides the 1-block/CU occupancy from the compiler's heuristic).
// ONE RMW arrival per block per step: relaxed publishes -> syncthreads (HW
// drains vmcnt for every wave before s_barrier) -> tid0 fetch_add + poll.

#define SMEM_FLOATS 35664

__global__ void __attribute__((amdgpu_flat_work_group_size(512, 512), amdgpu_waves_per_eu(2, 2)))
rim_scan(
    const float* __restrict__ Wq, const float* __restrict__ Wih, const float* __restrict__ Whh,
    const float* __restrict__ b_lstm, const float* __restrict__ Wqc, const float* __restrict__ Wkc,
    const float* __restrict__ Wvc,
    const float* __restrict__ keys, const float* __restrict__ vals,
    float* __restrict__ hidden,
    unsigned* __restrict__ bar, float* __restrict__ null_g,
    float* __restrict__ kcg, float* __restrict__ vcg)
{
    if (blockIdx.x & 7) return;                 // XCD-pinning dummies
    const int mech = blockIdx.x >> 3;

    extern __shared__ float sm[];
    float* swq  = sm;            // 8192  Wq_T  [64 out][128 K] swizzled
    float* swqc = sm + 8192;     // 4096  Wqc_T [32][128]
    float* swkc = sm + 12288;    // 4096  Wkc_T [32][128]
    float* swvc = sm + 16384;    // 16384 Wvc_T [128][128]
    float* skey = sm + 32768;    // 2*384 key double-buffer
    float* sval = sm + 33536;    // 2*384 val double-buffer
    float* sqp  = sm + 34304;    // 512   q partials (8 segs x 64)
    float* sh   = sm + 34816;    // 128   h state
    float* shn  = sm + 34944;    // 128   h_new candidate
    float* sop  = sm + 35072;    // 192   gate operand: [inp(64) | h(128)]
    float* qcl  = sm + 35264;    // 64    qc[var][32]
    float* kcl  = sm + 35328;    // 64    kc[var][32]
    float* vcl  = sm + 35392;    // 256   vc[var][128]
    float* slog = sm + 35648;    // 8     ctx logits
    float* snull= sm + 35656;    // 8

    const int tid = threadIdx.x;
    const int lane = tid & 63, wv = tid >> 6;

    // ---- stage transposed+swizzled weights into LDS
    for (int idx = tid; idx < 8192; idx += 512) {
        const int i = idx >> 6, j = idx & 63;
        swq[j * 128 + ((((i >> 2) ^ (j & 7)) << 2) | (i & 3))] = Wq[mech * 8192 + idx];
    }
    for (int idx = tid; idx < 4096; idx += 512) {
        const int i = idx >> 5, c = idx & 31;
        const int pos = c * 128 + ((((i >> 2) ^ (c & 7)) << 2) | (i & 3));
        swqc[pos] = Wqc[mech * 4096 + idx];
        swkc[pos] = Wkc[mech * 4096 + idx];
    }
    for (int idx = tid; idx < 16384; idx += 512) {
        const int i = idx >> 7, o = idx & 127;
        swvc[o * 128 + ((((i >> 2) ^ (o & 7)) << 2) | (i & 3))] = Wvc[mech * 16384 + idx];
    }
    if (tid < 384) { skey[tid] = keys[tid]; sval[tid] = vals[tid]; }  // prime t=0
    if (tid < 192) sop[tid] = 0.f;
    if (tid < 128) { sh[tid] = 0.f; shn[tid] = 0.f; }

    // ---- gate weights in registers. pair quad layout: threads 4j..4j+3 cover
    // cell j's 4 gates: p even -> (i_j, g_j), p odd -> (f_j, o_j); s = K-half.
    const int pair = tid >> 1, s = tid & 1;
    const int o0 = (pair >> 1) + (pair & 1) * 128;   // i_j or f_j
    const int o1 = o0 + 256;                          // g_j or o_j
    float wA[96], wB[96];
    if (s == 0) {
        #pragma unroll
        for (int k = 0; k < 64; ++k) {
            wA[k] = Wih[mech * 32768 + k * 512 + o0];
            wB[k] = Wih[mech * 32768 + k * 512 + o1];
        }
        #pragma unroll
        for (int k = 0; k < 32; ++k) {
            wA[64 + k] = Whh[mech * 65536 + k * 512 + o0];
            wB[64 + k] = Whh[mech * 65536 + k * 512 + o1];
        }
    } else {
        #pragma unroll
        for (int k = 0; k < 96; ++k) {
            wA[k] = Whh[mech * 65536 + (32 + k) * 512 + o0];
            wB[k] = Whh[mech * 65536 + (32 + k) * 512 + o1];
        }
    }
    const float b0v = (s == 0) ? b_lstm[mech * 512 + o0] : 0.f;
    const float b1v = (s == 0) ? b_lstm[mech * 512 + o1] : 0.f;
    float c_reg = 0.f, cn = 0.f;
    __syncthreads();

    #pragma unroll 1
    for (int t = 0; t < T_LEN; ++t) {
        const int par = t & 1;
        const float* kb = skey + par * 384;
        const float* vb = sval + par * 384;

        // qc/kc matvec (waves 1-2), per-variant; relaxed stores, NO arrival
        auto qckc = [&](const float* hsrc, int var) {
            const int idx2 = tid - 64, cc = idx2 >> 1, s2 = idx2 & 1;
            const float* wrow = (cc < 32) ? (swqc + cc * 128) : (swkc + (cc - 32) * 128);
            const int rx = cc & 7;
            const float4* h4 = (const float4*)(hsrc + s2 * 64);
            float p = 0.f;
            #pragma unroll
            for (int j = 0; j < 16; ++j) {
                const float4 w = *(const float4*)(wrow + (((s2 * 16 + j) ^ rx) << 2));
                const float4 hv = h4[j];
                p += w.x * hv.x + w.y * hv.y + w.z * hv.z + w.w * hv.w;
            }
            p += __shfl_xor(p, 1);
            if (s2 == 0) {
                if (cc < 32) qcl[var * 32 + cc] = p;
                else {
                    kcl[var * 32 + (cc - 32)] = p;
                    __hip_atomic_store(&kcg[((par * 5 + mech) * 2 + var) * 32 + (cc - 32)],
                                       p, __ATOMIC_RELAXED, AGT);
                }
            }
        };
        // vc matvec (waves 3-6), per-variant; relaxed stores, NO arrival
        auto vcf = [&](const float* hsrc, int var) {
            const int idx3 = tid - 192, o = idx3 >> 1, s3 = idx3 & 1;
            const float* wrow = swvc + o * 128;
            const int rx = o & 7;
            const float4* h4 = (const float4*)(hsrc + s3 * 64);
            float p = 0.f;
            #pragma unroll
            for (int j = 0; j < 16; ++j) {
                const float4 w = *(const float4*)(wrow + (((s3 * 16 + j) ^ rx) << 2));
                const float4 hv = h4[j];
                p += w.x * hv.x + w.y * hv.y + w.z * hv.z + w.w * hv.w;
            }
            p += __shfl_xor(p, 1);
            if (s3 == 0) {
                vcl[var * 128 + o] = p;
                __hip_atomic_store(&vcg[((par * 5 + mech) * 2 + var) * 128 + o],
                                   p, __ATOMIC_RELAXED, AGT);
            }
        };

        // ---- S0: q partials (all 8 waves; K-segment = wave)
        {
            const int out = lane, rx = out & 7;
            const float* wrow = swq + out * 128;
            const float4* h4 = (const float4*)(sh + wv * 16);
            float acc = 0.f;
            #pragma unroll
            for (int j = 0; j < 4; ++j) {
                const float4 w = *(const float4*)(wrow + (((wv * 4 + j) ^ rx) << 2));
                const float4 hv = h4[j];
                acc += w.x * hv.x + w.y * hv.y + w.z * hv.z + w.w * hv.w;
            }
            sqp[wv * 64 + out] = acc;
        }
        __syncthreads();

        // ---- S1: w0 attn+softmax+inp+null | w1-2 qc0/kc0 | w3-6 vc0 | w7 prefetch
        if (wv == 0) {
            float q = 0.f;
            #pragma unroll
            for (int k = 0; k < 8; ++k) q += sqp[k * 64 + lane];
            float l[6];
            #pragma unroll
            for (int k = 0; k < 6; ++k) {
                float p = q * kb[k * 64 + lane];
                p += __shfl_down(p, 32); p += __shfl_down(p, 16); p += __shfl_down(p, 8);
                p += __shfl_down(p, 4);  p += __shfl_down(p, 2);  p += __shfl_down(p, 1);
                l[k] = __shfl(p, 0) * 0.125f;
            }
            const float mx = fmaxf(fmaxf(fmaxf(l[0], l[1]), fmaxf(l[2], l[3])), fmaxf(l[4], l[5]));
            const float e0 = __expf(l[0] - mx), e1 = __expf(l[1] - mx), e2 = __expf(l[2] - mx);
            const float e3 = __expf(l[3] - mx), e4 = __expf(l[4] - mx), e5 = __expf(l[5] - mx);
            const float inv = 1.f / (e0 + e1 + e2 + e3 + e4 + e5);
            sop[lane] = (e0 * vb[lane] + e1 * vb[64 + lane] + e2 * vb[128 + lane]
                       + e3 * vb[192 + lane] + e4 * vb[256 + lane] + e5 * vb[320 + lane]) * inv;
            if (lane == 0)
                __hip_atomic_store(&null_g[par * 8 + mech], e5 * inv, __ATOMIC_RELAXED, AGT);
        } else if (wv <= 2) {
            qckc(sh, 0);
        } else if (wv <= 6) {
            vcf(sh, 0);
        } else {
            const int tn = (t < T_LEN - 1) ? t + 1 : t;
            const int nx = (t + 1) & 1;
            const float4* kn = (const float4*)(keys + tn * 384);
            const float4* vn = (const float4*)(vals + tn * 384);
            float4* kd = (float4*)(skey + nx * 384);
            float4* vd = (float4*)(sval + nx * 384);
            #pragma unroll
            for (int rep = 0; rep < 3; ++rep) {
                const int i = rep * 64 + lane;
                if (i < 96) kd[i] = kn[i];
                else if (i < 192) vd[i - 96] = vn[i - 96];
            }
        }
        __syncthreads();

        // ---- S2: gates in regs + LSTM via quad shuffles (no LDS round-trip)
        {
            const float4* op = (const float4*)(sop + s * 96);
            float p0 = b0v, p1 = b1v;
            #pragma unroll
            for (int q = 0; q < 24; ++q) {
                const float4 v = op[q];
                p0 += v.x * wA[4 * q] + v.y * wA[4 * q + 1] + v.z * wA[4 * q + 2] + v.w * wA[4 * q + 3];
                p1 += v.x * wB[4 * q] + v.y * wB[4 * q + 1] + v.z * wB[4 * q + 2] + v.w * wB[4 * q + 3];
            }
            const float r0 = p0 + __shfl_xor(p0, 1);   // gate o0 (full K)
            const float r1 = p1 + __shfl_xor(p1, 1);   // gate o1
            const float t0 = __shfl_xor(r0, 2);        // partner pair's o0
            const float t1 = __shfl_xor(r1, 2);        // partner pair's o1
            const bool even = ((pair & 1) == 0);
            const float gi = even ? r0 : t0;
            const float gg = even ? r1 : t1;
            const float gf = even ? t0 : r0;
            const float go = even ? t1 : r1;
            const float si = 1.f / (1.f + __expf(-gi));
            const float sf = 1.f / (1.f + __expf(-gf));
            const float so = 1.f / (1.f + __expf(-go));
            cn = sf * c_reg + si * tanh_f(gg);
            const float hn = so * tanh_f(cn);
            if ((tid & 3) == 0) shn[tid >> 2] = hn;
        }
        __syncthreads();

        // ---- S4: variant-1 matvecs (h_new)
        if (wv >= 1 && wv <= 2) qckc(shn, 1);
        else if (wv >= 3 && wv <= 6) vcf(shn, 1);
        __syncthreads();   // drains every wave's vmem (vmcnt(0) before s_barrier)

        // ---- BAR: single arrival per block, poll, fetch nulls
        if (tid == 0) {
            __hip_atomic_fetch_add(bar, 1u, __ATOMIC_RELAXED, AGT);
            const unsigned tgt = 5u * (unsigned)(t + 1);
            while (__hip_atomic_load(bar, __ATOMIC_RELAXED, AGT) < tgt)
                __builtin_amdgcn_s_sleep(1);
            asm volatile("" ::: "memory");
            #pragma unroll
            for (int mm = 0; mm < 5; ++mm)
                snull[mm] = __hip_atomic_load(&null_g[par * 8 + mm], __ATOMIC_RELAXED, AGT);
        }
        __syncthreads();

        // ---- S5: mask, c update, ctx logits (waves 3-7), remote vc loads (tid<128)
        int selfAct;
        {
            const float myn = snull[mech]; int r = 0;
            #pragma unroll
            for (int mm = 0; mm < 5; ++mm) {
                const float o = snull[mm];
                r += (o < myn || (o == myn && mm < mech)) ? 1 : 0;
            }
            selfAct = (r < 3) ? 1 : 0;
        }
        c_reg = selfAct ? cn : c_reg;
        float v0 = 0.f, v1 = 0.f, v2 = 0.f, v3 = 0.f, v4 = 0.f;
        if (wv >= 3 && lane < 32) {
            const int m2 = wv - 3;
            const float nm = snull[m2]; int r2 = 0;
            #pragma unroll
            for (int mm = 0; mm < 5; ++mm) {
                const float o = snull[mm];
                r2 += (o < nm || (o == nm && mm < m2)) ? 1 : 0;
            }
            const int sel2 = (r2 < 3) ? 1 : 0;
            const float kcv = (m2 == mech) ? kcl[sel2 * 32 + lane]
                : __hip_atomic_load(&kcg[((par * 5 + m2) * 2 + sel2) * 32 + lane], __ATOMIC_RELAXED, AGT);
            float p = qcl[selfAct * 32 + lane] * kcv;
            p += __shfl_down(p, 16); p += __shfl_down(p, 8); p += __shfl_down(p, 4);
            p += __shfl_down(p, 2);  p += __shfl_down(p, 1);
            if (lane == 0) slog[m2] = p * 0.17677669529663687f;
        }
        if (tid < 128) {
            int sel[5];
            #pragma unroll
            for (int mm = 0; mm < 5; ++mm) {
                const float nm = snull[mm]; int rr = 0;
                #pragma unroll
                for (int m3 = 0; m3 < 5; ++m3) {
                    const float o = snull[m3];
                    rr += (o < nm || (o == nm && m3 < mm)) ? 1 : 0;
                }
                sel[mm] = (rr < 3) ? 1 : 0;
            }
            v0 = (mech == 0) ? vcl[sel[0] * 128 + tid]
               : __hip_atomic_load(&vcg[((par * 5 + 0) * 2 + sel[0]) * 128 + tid], __ATOMIC_RELAXED, AGT);
            v1 = (mech == 1) ? vcl[sel[1] * 128 + tid]
               : __hip_atomic_load(&vcg[((par * 5 + 1) * 2 + sel[1]) * 128 + tid], __ATOMIC_RELAXED, AGT);
            v2 = (mech == 2) ? vcl[sel[2] * 128 + tid]
               : __hip_atomic_load(&vcg[((par * 5 + 2) * 2 + sel[2]) * 128 + tid], __ATOMIC_RELAXED, AGT);
            v3 = (mech == 3) ? vcl[sel[3] * 128 + tid]
               : __hip_atomic_load(&vcg[((par * 5 + 3) * 2 + sel[3]) * 128 + tid], __ATOMIC_RELAXED, AGT);
            v4 = (mech == 4) ? vcl[sel[4] * 128 + tid]
               : __hip_atomic_load(&vcg[((par * 5 + 4) * 2 + sel[4]) * 128 + tid], __ATOMIC_RELAXED, AGT);
        }
        __syncthreads();

        // ---- S6: ctx softmax + h2 + hidden store
        if (tid < 128) {
            const float l0 = slog[0], l1 = slog[1], l2 = slog[2], l3 = slog[3], l4 = slog[4];
            const float mx = fmaxf(fmaxf(fmaxf(l0, l1), fmaxf(l2, l3)), l4);
            const float e0 = __expf(l0 - mx), e1 = __expf(l1 - mx), e2 = __expf(l2 - mx);
            const float e3 = __expf(l3 - mx), e4 = __expf(l4 - mx);
            const float inv = 1.f / (e0 + e1 + e2 + e3 + e4);
            float hv = selfAct ? shn[tid] : sh[tid];
            if (selfAct) hv += (e0 * v0 + e1 * v1 + e2 * v2 + e3 * v3 + e4 * v4) * inv;
            sh[tid] = hv;
            sop[64 + tid] = hv;
            hidden[t * 640 + mech * 128 + tid] = hv;
        }
        __syncthreads();
    }
}

// ============ kernel 3: classifier ============
__global__ __launch_bounds__(256) void cls_kernel(
    const float* __restrict__ hidden, const float* __restrict__ Wcls,
    const float* __restrict__ bcls, float* __restrict__ out)
{
    const int t = blockIdx.x * 256 + threadIdx.x;
    if (t >= T_LEN) return;
    float a0 = bcls[0], a1 = bcls[1];
    for (int d = 0; d < 640; ++d) {
        const float h = hidden[t * 640 + d];
        a0 += h * Wcls[d * 2 + 0];
        a1 += h * Wcls[d * 2 + 1];
    }
    out[t * 2 + 0] = a0;
    out[t * 2 + 1] = a1;
}

extern "C" void kernel_launch(void* const* d_in, const int* in_sizes, int n_in,
                              void* d_out, int out_size, void* d_ws, size_t ws_size,
                              hipStream_t stream)
{
    (void)in_sizes; (void)n_in; (void)out_size; (void)ws_size;
    const float* bert  = (const float*)d_in[0];
    const int*   uidx  = (const int*)d_in[1];
    const int*   pidx  = (const int*)d_in[2];
    const float* disg  = (const float*)d_in[3];
    const float* udisg = (const float*)d_in[4];
    const float* utab  = (const float*)d_in[5];
    const float* ptab  = (const float*)d_in[6];
    const float* Wk0 = (const float*)d_in[7],  *Wv0 = (const float*)d_in[8];
    const float* Wk1 = (const float*)d_in[9],  *Wv1 = (const float*)d_in[10];
    const float* Wk2 = (const float*)d_in[11], *Wv2 = (const float*)d_in[12];
    const float* Wk3 = (const float*)d_in[13], *Wv3 = (const float*)d_in[14];
    const float* Wk4 = (const float*)d_in[15], *Wv4 = (const float*)d_in[16];
    const float* Wq   = (const float*)d_in[17];
    const float* Wih  = (const float*)d_in[18];
    const float* Whh  = (const float*)d_in[19];
    const float* bl   = (const float*)d_in[20];
    const float* Wqc  = (const float*)d_in[21];
    const float* Wkc  = (const float*)d_in[22];
    const float* Wvc  = (const float*)d_in[23];
    const float* Wcls = (const float*)d_in[24];
    const float* bcls = (const float*)d_in[25];

    char* ws = (char*)d_ws;
    unsigned* bar  = (unsigned*)ws;
    float* null_g  = (float*)(ws + 0x100);
    float* kcg     = (float*)(ws + 0x200);
    float* vcg     = (float*)(ws + 0xC00);
    float* keys    = (float*)(ws + 0x4000);
    float* vals    = (float*)(ws + 0x4000 + 786432);
    float* hidden  = (float*)(ws + 0x4000 + 2 * 786432);

    hipMemsetAsync(d_ws, 0, 256, stream);   // zero barrier counter

    hipLaunchKernelGGL(precompute_kv, dim3(T_LEN), dim3(128), 0, stream,
        bert, uidx, pidx, disg, udisg, utab, ptab,
        Wk0, Wv0, Wk1, Wv1, Wk2, Wv2, Wk3, Wv3, Wk4, Wv4, keys, vals);

    const int smem_bytes = SMEM_FLOATS * 4;   // 142656 B < 160 KiB
    (void)hipFuncSetAttribute((const void*)rim_scan,
                              hipFuncAttributeMaxDynamicSharedMemorySize, smem_bytes);
    hipLaunchKernelGGL(rim_scan, dim3(40), dim3(512), smem_bytes, stream,
        Wq, Wih, Whh, bl, Wqc, Wkc, Wvc, keys, vals, hidden, bar, null_g, kcg, vcg);

    hipLaunchKernelGGL(cls_kernel, dim3(2), dim3(256), 0, stream,
        hidden, Wcls, bcls, (float*)d_out);
}